// Round 9
// baseline (258.312 us; speedup 1.0000x reference)
//
#include <hip/hip_runtime.h>
#include <float.h>
#include <math.h>
#include <stdint.h>

#define B_   8
#define L_   512
#define H_   768
#define W_   5
#define K_   32
#define P_   256
#define EPS_ 1e-5f
#define NEG_ -1e30f

typedef _Float16 half8 __attribute__((ext_vector_type(8)));
typedef _Float16 half4v __attribute__((ext_vector_type(4)));
typedef float floatx4 __attribute__((ext_vector_type(4)));

// ---------------- ws layout (float units) ----------------
static const size_t OFF_X   = 0;                   // 4096*2304 f32
static const size_t OFF_AH  = 9437184;             // 4096*768 f16 (hi)
static const size_t OFF_AL  = 11010048;            // 4096*768 f16 (lo)
static const size_t OFF_BH  = 12582912;            // 2304*768 f16 (WtT hi)
static const size_t OFF_BL  = 13467648;            // 2304*768 f16 (WtT lo)
static const size_t OFF_SC  = 14352384;            // 8*2560 scores
static const size_t OFF_TS  = 14372864;            // 256
static const size_t OFF_TI  = 14373120;            // 256 (int)
static const size_t OFF_GL  = 14373376;            // 256 gate logits
static const size_t OFF_EMB = 14373632;            // 256*768
static const size_t OFF_Y   = 14570240;            // 256*640

#define A_SCALE 8.0f
#define B_SCALE 64.0f
#define INV_SCALE (1.0f / 512.0f)

// ---------------- kernel 1: fused prep: split hidden + build WtT hi/lo ----------------
__global__ __launch_bounds__(256) void prep_kernel(const float* __restrict__ hid,
                                                   const float* __restrict__ w1,
                                                   _Float16* __restrict__ ah,
                                                   _Float16* __restrict__ al,
                                                   _Float16* __restrict__ bh,
                                                   _Float16* __restrict__ bl) {
    __shared__ float ld[64][65];
    if (blockIdx.x < 3072) {
        int idx = (blockIdx.x * 256 + threadIdx.x) * 4;
        float4 x = *(const float4*)(hid + idx);
        float xs[4] = {x.x * A_SCALE, x.y * A_SCALE, x.z * A_SCALE, x.w * A_SCALE};
        half4v h, l;
#pragma unroll
        for (int i = 0; i < 4; ++i) {
            _Float16 hi = (_Float16)xs[i];
            h[i] = hi;
            l[i] = (_Float16)(xs[i] - (float)hi);
        }
        *(half4v*)(ah + idx) = h;
        *(half4v*)(al + idx) = l;
    } else {
        int bid = blockIdx.x - 3072;          // 0..431
        int n0 = (bid / 12) * 64;
        int k0 = (bid % 12) * 64;
        int t = threadIdx.x;
        int rsel = n0 / 768;
        int c0 = n0 - rsel * 768;
#pragma unroll 4
        for (int r = 0; r < 16; ++r) {
            int idx = r * 256 + t;
            int kk = idx >> 6, nn = idx & 63;
            int k = k0 + kk, c = c0 + nn;
            float v;
            if (rsel == 0)      v = w1[(size_t)k * 768 + c] - w1[(size_t)(2304 + k) * 768 + c];
            else if (rsel == 1) v = w1[(size_t)(768 + k) * 768 + c] + w1[(size_t)(2304 + k) * 768 + c];
            else                v = w1[(size_t)(1536 + k) * 768 + c];
            ld[kk][nn] = v * B_SCALE;
        }
        __syncthreads();
#pragma unroll 4
        for (int r = 0; r < 16; ++r) {
            int idx = r * 256 + t;
            int nn = idx >> 6, kk = idx & 63;
            float v = ld[kk][nn];
            _Float16 h = (_Float16)v;
            _Float16 lo = (_Float16)(v - (float)h);
            size_t o = (size_t)(n0 + nn) * 768 + k0 + kk;
            bh[o] = h;
            bl[o] = lo;
        }
    }
}

// ---------------- kernel 2: split-f16 MFMA GEMM, 128x64 tile ---------------------------
// A via LDS double-buffer (barrier-coupled DMA halved: 16 KB/iter), B via register
// prefetch straight from global (L2-resident, loaded one iteration ahead).
typedef const __attribute__((address_space(1))) void* gas_ptr;
typedef __attribute__((address_space(3))) void* las_ptr;
__device__ __forceinline__ void async_ld16(const _Float16* g, _Float16* l) {
    __builtin_amdgcn_global_load_lds((gas_ptr)g, (las_ptr)l, 16, 0, 0);
}

__global__ __launch_bounds__(256) void mfma_gemm_kernel(const _Float16* __restrict__ Ah,
                                                        const _Float16* __restrict__ Al,
                                                        const _Float16* __restrict__ Bh,
                                                        const _Float16* __restrict__ Bl,
                                                        float* __restrict__ C) {
    __shared__ _Float16 sAh[2 * 4096];   // [parity][128 rows x 32 k]
    __shared__ _Float16 sAl[2 * 4096];
    int tid = threadIdx.x;
    int lane = tid & 63;
    int wave = tid >> 6;
    int m0 = blockIdx.x * 128, n0 = blockIdx.y * 64;

    // A staging: wave w stages 4 chunks of (w<2 ? Ah : Al); chunk = 16 rows x 32 k.
    const _Float16* src = (wave < 2) ? Ah : Al;
    _Float16* dstb = (wave < 2) ? sAh : sAl;
    int co = (wave & 1) * 4;                            // chunk offset: rows co*16
    int qg = (lane & 3) ^ ((lane >> 3) & 3);            // swizzled source k-group
    const _Float16* gp = src + (size_t)(m0 + co * 16 + (lane >> 2)) * 768 + qg * 8;

    // compute role: wave -> 64x32 quadrant
    int wr = wave >> 1, wc = wave & 1;
    int off_lane = (lane & 15) * 64 + (((lane >> 4) ^ ((lane >> 1) & 3)) * 16);  // bytes

    // B fragment pointers (direct global): lane holds B[n = base + (lane&15)][k0 + (lane>>4)*8 .. +8]
    const _Float16* bhp = Bh + (size_t)(n0 + wc * 32 + (lane & 15)) * 768 + ((lane >> 4) * 8);
    const _Float16* blp = Bl + (size_t)(n0 + wc * 32 + (lane & 15)) * 768 + ((lane >> 4) * 8);

    floatx4 acc[4][2];
#pragma unroll
    for (int i = 0; i < 4; ++i)
#pragma unroll
        for (int j = 0; j < 2; ++j)
            acc[i][j] = (floatx4){0.f, 0.f, 0.f, 0.f};

    // prologue: stage A k0=0 into parity 0; load B frags for k0=0
#pragma unroll
    for (int c = 0; c < 4; ++c)
        async_ld16(gp + (size_t)c * 16 * 768, dstb + (co + c) * 512);
    half8 b_h[2], b_l[2], b_hn[2], b_ln[2];
#pragma unroll
    for (int j = 0; j < 2; ++j) {
        b_h[j] = *(const half8*)(bhp + (size_t)j * 16 * 768);
        b_l[j] = *(const half8*)(blp + (size_t)j * 16 * 768);
    }

    int parity = 0;
#pragma unroll
    for (int k0 = 0; k0 < 768; k0 += 32) {
        __syncthreads();   // A parity tile staged; prev parity's ds_reads done
        if (k0 + 32 < 768) {
            _Float16* dst = dstb + (parity ^ 1) * 4096;
            const _Float16* g = gp + k0 + 32;
#pragma unroll
            for (int c = 0; c < 4; ++c)
                async_ld16(g + (size_t)c * 16 * 768, dst + (co + c) * 512);
#pragma unroll
            for (int j = 0; j < 2; ++j) {
                b_hn[j] = *(const half8*)(bhp + (size_t)j * 16 * 768 + k0 + 32);
                b_ln[j] = *(const half8*)(blp + (size_t)j * 16 * 768 + k0 + 32);
            }
        }

        const char* bAh = (const char*)sAh + parity * 8192 + wr * 4096 + off_lane;
        const char* bAl = (const char*)sAl + parity * 8192 + wr * 4096 + off_lane;
        half8 a_h[4], a_l[4];
#pragma unroll
        for (int i = 0; i < 4; ++i) {
            a_h[i] = *(const half8*)(bAh + i * 1024);
            a_l[i] = *(const half8*)(bAl + i * 1024);
        }
#pragma unroll
        for (int i = 0; i < 4; ++i)
#pragma unroll
            for (int j = 0; j < 2; ++j) {
                acc[i][j] = __builtin_amdgcn_mfma_f32_16x16x32_f16(a_h[i], b_h[j], acc[i][j], 0, 0, 0);
                acc[i][j] = __builtin_amdgcn_mfma_f32_16x16x32_f16(a_h[i], b_l[j], acc[i][j], 0, 0, 0);
                acc[i][j] = __builtin_amdgcn_mfma_f32_16x16x32_f16(a_l[i], b_h[j], acc[i][j], 0, 0, 0);
            }
#pragma unroll
        for (int j = 0; j < 2; ++j) {
            b_h[j] = b_hn[j];
            b_l[j] = b_ln[j];
        }
        parity ^= 1;
    }

    int colc = lane & 15, quad = lane >> 4;
#pragma unroll
    for (int i = 0; i < 4; ++i) {
#pragma unroll
        for (int r = 0; r < 4; ++r) {
            int row = m0 + wr * 64 + i * 16 + quad * 4 + r;
            float* Cp = C + (size_t)row * 2304 + n0 + wc * 32 + colc;
#pragma unroll
            for (int j = 0; j < 2; ++j)
                Cp[j * 16] = acc[i][j][r] * INV_SCALE;
        }
    }
}

// ---------------- kernel 3: span scores; LDS row staging + fused sum/sumsq reduce -----
__global__ __launch_bounds__(256) void score_kernel(const float* __restrict__ X,
                                                    const int* __restrict__ mask,
                                                    const float* __restrict__ b1,
                                                    const float* __restrict__ g1,
                                                    const float* __restrict__ beta1,
                                                    const float* __restrict__ w2,
                                                    const float* __restrict__ b2,
                                                    float* __restrict__ scores) {
    __shared__ float sE[8 * 768];   // B-part (end) rows i0..i0+7 (clamped)
    __shared__ float sC[8 * 768];   // C-part (span-sum) rows
    int tid = threadIdx.x;
    int wv = tid >> 6, lane = tid & 63;
    int bi0 = blockIdx.x * 4;          // 1024 blocks
    int b = bi0 >> 9, i0 = bi0 & 511;

#pragma unroll
    for (int u0 = 0; u0 < 6; ++u0) {
        int u = u0 * 256 + tid;        // 0..1535
        int t = u / 192, f = u - t * 192;
        int j = min(i0 + t, 511);
        const float4* Xj = (const float4*)(X + (size_t)(b * 512 + j) * 2304);
        ((float4*)sE)[t * 192 + f] = Xj[192 + f];
        ((float4*)sC)[t * 192 + f] = Xj[384 + f];
    }

    int i = i0 + wv, bi = bi0 + wv;
    float4 a[3], b1c[3], g1c[3], btc[3], w2c[3], ss[3];
    const float4* Xrow = (const float4*)(X + (size_t)bi * 2304);
#pragma unroll
    for (int q = 0; q < 3; ++q) {
        int f = lane + q * 64;
        a[q]   = Xrow[f];
        b1c[q] = ((const float4*)b1)[f];
        g1c[q] = ((const float4*)g1)[f];
        btc[q] = ((const float4*)beta1)[f];
        w2c[q] = ((const float4*)w2)[f];
        ss[q]  = make_float4(0.f, 0.f, 0.f, 0.f);
    }
    float bias2 = b2[0];
    __syncthreads();

    int jcur = i - 1;
    float4 e[3];
    float sc_loc[W_];

    for (int w = 0; w < W_; ++w) {
        int j = min(i + w, 511);
        if (j > jcur) {
            int slot = j - i0;
#pragma unroll
            for (int q = 0; q < 3; ++q) {
                int f = lane + q * 64;
                float4 cc = ((const float4*)sC)[slot * 192 + f];
                ss[q].x += cc.x; ss[q].y += cc.y; ss[q].z += cc.z; ss[q].w += cc.w;
                e[q] = ((const float4*)sE)[slot * 192 + f];
            }
            jcur = j;
        }
        float invw = 1.0f / (float)(w + 1);
        float4 h[3];
        float psum = 0.f, psq = 0.f;
#pragma unroll
        for (int q = 0; q < 3; ++q) {
            h[q].x = a[q].x + e[q].x + ss[q].x * invw + b1c[q].x;
            h[q].y = a[q].y + e[q].y + ss[q].y * invw + b1c[q].y;
            h[q].z = a[q].z + e[q].z + ss[q].z * invw + b1c[q].z;
            h[q].w = a[q].w + e[q].w + ss[q].w * invw + b1c[q].w;
            psum += h[q].x + h[q].y + h[q].z + h[q].w;
            psq  += h[q].x * h[q].x + h[q].y * h[q].y + h[q].z * h[q].z + h[q].w * h[q].w;
        }
#pragma unroll
        for (int m = 1; m < 64; m <<= 1) {
            psum += __shfl_xor(psum, m, 64);
            psq  += __shfl_xor(psq, m, 64);
        }
        float mean = psum * (1.f / 768.f);
        float var  = psq * (1.f / 768.f) - mean * mean;
        float rstd = rsqrtf(var + EPS_);

        float pd = 0.f;
#pragma unroll
        for (int q = 0; q < 3; ++q) {
            float yx = fmaxf((h[q].x - mean) * rstd * g1c[q].x + btc[q].x, 0.f);
            float yy = fmaxf((h[q].y - mean) * rstd * g1c[q].y + btc[q].y, 0.f);
            float yz = fmaxf((h[q].z - mean) * rstd * g1c[q].z + btc[q].z, 0.f);
            float yw = fmaxf((h[q].w - mean) * rstd * g1c[q].w + btc[q].w, 0.f);
            pd += yx * w2c[q].x + yy * w2c[q].y + yz * w2c[q].z + yw * w2c[q].w;
        }
#pragma unroll
        for (int m = 1; m < 64; m <<= 1) pd += __shfl_xor(pd, m, 64);
        sc_loc[w] = pd + bias2;
    }

    if (lane < W_) {
        int w = lane;
        bool ok = (i + w) < 512;
        if (ok) {
            for (int t = 0; t <= w; ++t) ok = ok && (mask[b * 512 + i + t] != 0);
        }
        scores[b * 2560 + i * 5 + w] = ok ? sc_loc[w] : NEG_;
    }
}

// ---------------- kernel 4: per-b top-32 via u64 keys + register heads ----------------
__device__ __forceinline__ uint64_t shfl_xor_u64(uint64_t x, int m) {
    uint32_t lo = (uint32_t)x, hi = (uint32_t)(x >> 32);
    lo = (uint32_t)__shfl_xor((int)lo, m, 64);
    hi = (uint32_t)__shfl_xor((int)hi, m, 64);
    return ((uint64_t)hi << 32) | lo;
}

__global__ __launch_bounds__(256) void topk_kernel(const float* __restrict__ scores,
                                                   float* __restrict__ tops,
                                                   int* __restrict__ topi,
                                                   float* __restrict__ out_masks,
                                                   float* __restrict__ out_scores,
                                                   float* __restrict__ out_spans) {
    int b = blockIdx.x;
    int tid = threadIdx.x;
    int lane = tid & 63;
    int wv = tid >> 6;
    __shared__ uint64_t lists[256 * 9];
    __shared__ uint64_t wmax[4];
    __shared__ uint64_t gS;

    uint64_t v[10];
#pragma unroll
    for (int q = 0; q < 10; ++q) {
        int t = q * 256 + tid;
        float f = scores[b * 2560 + t];
        uint32_t bits = __float_as_uint(f);
        uint32_t mk = bits ^ ((bits & 0x80000000u) ? 0xFFFFFFFFu : 0x80000000u);
        v[q] = ((uint64_t)mk << 32) | (uint64_t)(0xFFFFFFFFu - (uint32_t)t);
    }
#pragma unroll
    for (int p = 0; p < 5; ++p) {
#pragma unroll
        for (int i = 0; i < 9; i += 2) {
            if (v[i] < v[i + 1]) { uint64_t t = v[i]; v[i] = v[i + 1]; v[i + 1] = t; }
        }
#pragma unroll
        for (int i = 1; i < 9; i += 2) {
            if (v[i] < v[i + 1]) { uint64_t t = v[i]; v[i] = v[i + 1]; v[i + 1] = t; }
        }
    }
#pragma unroll
    for (int j = 0; j < 9; ++j) lists[tid * 9 + j] = v[j + 1];
    uint64_t my = v[0];
    int h = 0;

    for (int k = 0; k < K_; ++k) {
        uint64_t m = my;
#pragma unroll
        for (int s = 1; s < 64; s <<= 1) {
            uint64_t o = shfl_xor_u64(m, s);
            if (o > m) m = o;
        }
        if (lane == 0) wmax[wv] = m;
        __syncthreads();
        if (tid == 0) {
            uint64_t g = wmax[0];
#pragma unroll
            for (int q = 1; q < 4; ++q) if (wmax[q] > g) g = wmax[q];
            gS = g;
            uint32_t mk = (uint32_t)(g >> 32);
            uint32_t bits = mk ^ ((mk & 0x80000000u) ? 0x80000000u : 0xFFFFFFFFu);
            float tv = __uint_as_float(bits);
            int tix = (int)(0xFFFFFFFFu - (uint32_t)(g & 0xFFFFFFFFu));
            tops[b * 32 + k] = tv;
            topi[b * 32 + k] = tix;
            bool mm = tv > (NEG_ * 0.5f);
            out_masks[b * 32 + k] = mm ? 1.0f : 0.0f;
            out_scores[b * 32 + k] = mm ? tv : -10.0f;
            int tI = tix / 5, tw = tix % 5;
            out_spans[(b * 32 + k) * 2 + 0] = mm ? (float)tI : 0.0f;
            out_spans[(b * 32 + k) * 2 + 1] = mm ? (float)(tI + tw) : 0.0f;
        }
        __syncthreads();
        uint64_t g = gS;
        if (my == g) {
            my = (h < 9) ? lists[tid * 9 + h] : 0ull;
            ++h;
        }
    }
}

// ---------------- kernel 5: gather phrase mean-embeddings into Embs[256][768] ---------
__global__ __launch_bounds__(256) void gather_emb_kernel(const float* __restrict__ hidden,
                                                         const float* __restrict__ tops,
                                                         const int* __restrict__ topi,
                                                         float* __restrict__ Embs) {
    int bk = blockIdx.x;            // 0..255
    int b = bk >> 5;
    int tid = threadIdx.x;
    int idx = topi[bk];
    bool valid = tops[bk] > (NEG_ * 0.5f);
    int tI = idx / 5, tw = idx % 5;
    int jend = min(tI + tw, L_ - 1);
    float inv = 1.0f / (float)(tw + 1);
#pragma unroll
    for (int q = 0; q < 3; ++q) {
        int c = tid + q * 256;
        float s = 0.f;
        if (valid) {
            for (int l = tI; l <= jend; ++l) s += hidden[(size_t)(b * 512 + l) * 768 + c];
            s *= inv;
        }
        Embs[(size_t)bk * 768 + c] = s;
    }
}

// ---------------- kernel 6: Y[256][640] = Embs @ [wg1|wp] + [bg1|bp] ----------------
__global__ __launch_bounds__(256) void phrase_gemm_kernel(const float* __restrict__ Embs,
                                                          const float* __restrict__ wg1,
                                                          const float* __restrict__ bg1,
                                                          const float* __restrict__ wp,
                                                          const float* __restrict__ bp,
                                                          float* __restrict__ Y) {
    __shared__ float As[32][34];   // [k][r]
    __shared__ float Bs[32][64];   // [k][c]
    int tid = threadIdx.x;
    int m0 = blockIdx.x * 32;
    int cn0 = blockIdx.y * 64;
    const float* Wp; const float* biasp; int ldw;
    if (cn0 < 384) { Wp = wg1 + cn0;        biasp = bg1 + cn0;        ldw = 384; }
    else           { Wp = wp + (cn0 - 384); biasp = bp + (cn0 - 384); ldw = 256; }

    int tx = tid & 15;       // cols tx*4
    int ty = tid >> 4;       // rows ty*2
    int ar = tid >> 3, akq = (tid & 7) * 4;
    int bk = tid >> 3, bcq = (tid & 7) * 8;
    float acc[2][4] = {};

    for (int k0 = 0; k0 < 768; k0 += 32) {
        float4 av  = *(const float4*)(Embs + (size_t)(m0 + ar) * 768 + k0 + akq);
        float4 bv0 = *(const float4*)(Wp + (size_t)(k0 + bk) * ldw + bcq);
        float4 bv1 = *(const float4*)(Wp + (size_t)(k0 + bk) * ldw + bcq + 4);
        __syncthreads();
        As[akq + 0][ar] = av.x;
        As[akq + 1][ar] = av.y;
        As[akq + 2][ar] = av.z;
        As[akq + 3][ar] = av.w;
        *(float4*)&Bs[bk][bcq]     = bv0;
        *(float4*)&Bs[bk][bcq + 4] = bv1;
        __syncthreads();
#pragma unroll
        for (int kk = 0; kk < 32; ++kk) {
            float2 a = *(const float2*)&As[kk][ty * 2];
            float4 b = *(const float4*)&Bs[kk][tx * 4];
            acc[0][0] += a.x * b.x; acc[0][1] += a.x * b.y; acc[0][2] += a.x * b.z; acc[0][3] += a.x * b.w;
            acc[1][0] += a.y * b.x; acc[1][1] += a.y * b.y; acc[1][2] += a.y * b.z; acc[1][3] += a.y * b.w;
        }
    }
#pragma unroll
    for (int i = 0; i < 2; ++i) {
        float* Yp = Y + (size_t)(m0 + ty * 2 + i) * 640 + cn0 + tx * 4;
        float4 o = make_float4(acc[i][0] + biasp[tx * 4 + 0], acc[i][1] + biasp[tx * 4 + 1],
                               acc[i][2] + biasp[tx * 4 + 2], acc[i][3] + biasp[tx * 4 + 3]);
        *(float4*)Yp = o;
    }
}

// ---------------- kernel 7: per-row gate (tanh . wg2) + LN of projection --------------
__global__ __launch_bounds__(256) void phrase_post_kernel(const float* __restrict__ Y,
                                                          const float* __restrict__ wg2,
                                                          const float* __restrict__ bg2,
                                                          const float* __restrict__ tops,
                                                          const float* __restrict__ gout,
                                                          const float* __restrict__ bout,
                                                          float* __restrict__ gate,
                                                          float* __restrict__ out_embeds) {
    int wv = threadIdx.x >> 6, lane = threadIdx.x & 63;
    int row = blockIdx.x * 4 + wv;   // 64 blocks -> 256 rows
    const float* Yrow = Y + (size_t)row * 640;

    float s = 0.f;
#pragma unroll
    for (int q = 0; q < 6; ++q) {
        int c = lane + q * 64;
        s += tanhf(Yrow[c]) * wg2[c];
    }
#pragma unroll
    for (int m = 1; m < 64; m <<= 1) s += __shfl_xor(s, m, 64);
    if (lane == 0) {
        bool valid = tops[row] > (NEG_ * 0.5f);
        gate[row] = valid ? (s + bg2[0]) : -1e9f;
    }

    float4 p = *(const float4*)(Yrow + 384 + lane * 4);
    float sm = p.x + p.y + p.z + p.w;
#pragma unroll
    for (int m = 1; m < 64; m <<= 1) sm += __shfl_xor(sm, m, 64);
    float mean = sm * (1.f / 256.f);
    float dx = p.x - mean, dy = p.y - mean, dz = p.z - mean, dw = p.w - mean;
    float v = dx * dx + dy * dy + dz * dz + dw * dw;
#pragma unroll
    for (int m = 1; m < 64; m <<= 1) v += __shfl_xor(v, m, 64);
    float rstd = rsqrtf(v * (1.f / 256.f) + EPS_);
    int c = lane * 4;
    float4 o;
    o.x = dx * rstd * gout[c]     + bout[c];
    o.y = dy * rstd * gout[c + 1] + bout[c + 1];
    o.z = dz * rstd * gout[c + 2] + bout[c + 2];
    o.w = dw * rstd * gout[c + 3] + bout[c + 3];
    *(float4*)(out_embeds + (size_t)row * 256 + c) = o;
}

// ---------------- kernel 8: softmax over K per b ----------------
__global__ void attn_kernel(const float* __restrict__ gate, float* __restrict__ out_attn) {
    int b = threadIdx.x;
    if (b < 8) {
        float mx = -FLT_MAX;
        for (int k = 0; k < 32; ++k) mx = fmaxf(mx, gate[b * 32 + k]);
        float e[32];
        float s = 0.f;
        for (int k = 0; k < 32; ++k) { e[k] = expf(gate[b * 32 + k] - mx); s += e[k]; }
        float inv = 1.f / s;
        for (int k = 0; k < 32; ++k) out_attn[b * 32 + k] = e[k] * inv;
    }
}

extern "C" void kernel_launch(void* const* d_in, const int* in_sizes, int n_in,
                              void* d_out, int out_size, void* d_ws, size_t ws_size,
                              hipStream_t stream) {
    const float* hidden = (const float*)d_in[0];
    const int*   amask  = (const int*)d_in[1];
    const float* w1     = (const float*)d_in[2];
    const float* b1     = (const float*)d_in[3];
    const float* g1     = (const float*)d_in[4];
    const float* beta1  = (const float*)d_in[5];
    const float* w2     = (const float*)d_in[6];
    const float* b2     = (const float*)d_in[7];
    const float* wp     = (const float*)d_in[8];
    const float* bp     = (const float*)d_in[9];
    const float* wg1    = (const float*)d_in[10];
    const float* bg1    = (const float*)d_in[11];
    const float* wg2    = (const float*)d_in[12];
    const float* bg2    = (const float*)d_in[13];
    const float* gout   = (const float*)d_in[14];
    const float* bout   = (const float*)d_in[15];

    float* ws = (float*)d_ws;
    float*     X    = ws + OFF_X;
    _Float16*  ah   = (_Float16*)(ws + OFF_AH);
    _Float16*  al   = (_Float16*)(ws + OFF_AL);
    _Float16*  bh   = (_Float16*)(ws + OFF_BH);
    _Float16*  bl   = (_Float16*)(ws + OFF_BL);
    float*     sc   = ws + OFF_SC;
    float*     ts   = ws + OFF_TS;
    int*       ti   = (int*)(ws + OFF_TI);
    float*     gl   = ws + OFF_GL;
    float*     Embs = ws + OFF_EMB;
    float*     Y    = ws + OFF_Y;

    float* out = (float*)d_out;
    float* out_embeds = out;                   // 8*32*256 = 65536
    float* out_masks  = out + 65536;           // 256
    float* out_attn   = out + 65792;           // 256
    float* out_scores = out + 66048;           // 256
    float* out_spans  = out + 66304;           // 512

    prep_kernel<<<3504, 256, 0, stream>>>(hidden, w1, ah, al, bh, bl);
    mfma_gemm_kernel<<<dim3(32, 36), 256, 0, stream>>>(ah, al, bh, bl, X);
    score_kernel<<<1024, 256, 0, stream>>>(X, amask, b1, g1, beta1, w2, b2, sc);
    topk_kernel<<<8, 256, 0, stream>>>(sc, ts, ti, out_masks, out_scores, out_spans);
    gather_emb_kernel<<<256, 256, 0, stream>>>(hidden, ts, ti, Embs);
    phrase_gemm_kernel<<<dim3(8, 10), 256, 0, stream>>>(Embs, wg1, bg1, wp, bp, Y);
    phrase_post_kernel<<<64, 256, 0, stream>>>(Y, wg2, bg2, ts, gout, bout, gl, out_embeds);
    attn_kernel<<<1, 64, 0, stream>>>(gl, out_attn);
}

// Round 10
// 233.359 us; speedup vs baseline: 1.1069x; 1.1069x over previous
//
#include <hip/hip_runtime.h>
#include <float.h>
#include <math.h>
#include <stdint.h>

#define B_   8
#define L_   512
#define H_   768
#define W_   5
#define K_   32
#define P_   256
#define EPS_ 1e-5f
#define NEG_ -1e30f

typedef _Float16 half8 __attribute__((ext_vector_type(8)));
typedef _Float16 half4v __attribute__((ext_vector_type(4)));
typedef float floatx4 __attribute__((ext_vector_type(4)));

// ---------------- ws layout (float units) ----------------
static const size_t OFF_X   = 0;                   // 4096*2304 f32
static const size_t OFF_AH  = 9437184;             // 4096*768 f16 (hi)
static const size_t OFF_AL  = 11010048;            // 4096*768 f16 (lo)
static const size_t OFF_BH  = 12582912;            // 2304*768 f16 (WtT hi)
static const size_t OFF_BL  = 13467648;            // 2304*768 f16 (WtT lo)
static const size_t OFF_SC  = 14352384;            // 8*2560 scores
static const size_t OFF_TS  = 14372864;            // 256
static const size_t OFF_TI  = 14373120;            // 256 (int)
static const size_t OFF_GL  = 14373376;            // 256 gate logits
static const size_t OFF_EMB = 14373632;            // 256*768
static const size_t OFF_Y   = 14570240;            // 256*640

#define A_SCALE 8.0f
#define B_SCALE 64.0f
#define INV_SCALE (1.0f / 512.0f)

// ---------------- kernel 1: fused prep: split hidden + build WtT hi/lo ----------------
__global__ __launch_bounds__(256) void prep_kernel(const float* __restrict__ hid,
                                                   const float* __restrict__ w1,
                                                   _Float16* __restrict__ ah,
                                                   _Float16* __restrict__ al,
                                                   _Float16* __restrict__ bh,
                                                   _Float16* __restrict__ bl) {
    __shared__ float ld[64][65];
    if (blockIdx.x < 3072) {
        int idx = (blockIdx.x * 256 + threadIdx.x) * 4;
        float4 x = *(const float4*)(hid + idx);
        float xs[4] = {x.x * A_SCALE, x.y * A_SCALE, x.z * A_SCALE, x.w * A_SCALE};
        half4v h, l;
#pragma unroll
        for (int i = 0; i < 4; ++i) {
            _Float16 hi = (_Float16)xs[i];
            h[i] = hi;
            l[i] = (_Float16)(xs[i] - (float)hi);
        }
        *(half4v*)(ah + idx) = h;
        *(half4v*)(al + idx) = l;
    } else {
        int bid = blockIdx.x - 3072;          // 0..431
        int n0 = (bid / 12) * 64;
        int k0 = (bid % 12) * 64;
        int t = threadIdx.x;
        int rsel = n0 / 768;
        int c0 = n0 - rsel * 768;
#pragma unroll 4
        for (int r = 0; r < 16; ++r) {
            int idx = r * 256 + t;
            int kk = idx >> 6, nn = idx & 63;
            int k = k0 + kk, c = c0 + nn;
            float v;
            if (rsel == 0)      v = w1[(size_t)k * 768 + c] - w1[(size_t)(2304 + k) * 768 + c];
            else if (rsel == 1) v = w1[(size_t)(768 + k) * 768 + c] + w1[(size_t)(2304 + k) * 768 + c];
            else                v = w1[(size_t)(1536 + k) * 768 + c];
            ld[kk][nn] = v * B_SCALE;
        }
        __syncthreads();
#pragma unroll 4
        for (int r = 0; r < 16; ++r) {
            int idx = r * 256 + t;
            int nn = idx >> 6, kk = idx & 63;
            float v = ld[kk][nn];
            _Float16 h = (_Float16)v;
            _Float16 lo = (_Float16)(v - (float)h);
            size_t o = (size_t)(n0 + nn) * 768 + k0 + kk;
            bh[o] = h;
            bl[o] = lo;
        }
    }
}

// ---------------- kernel 2: split-f16 MFMA GEMM, 128x64 tile, LDS double-buffer ------
// (R8-measured best: 62 us, MfmaUtil 28.5%, Occ 24%, conflicts 0. Register B-prefetch
//  regressed to 89 us: the b_h=b_hn rotation forces a per-iter vmcnt wait with only
//  ~115 cyc of MFMA cover. 128x128 dbuf also regressed via 2-blocks/CU occupancy.)
typedef const __attribute__((address_space(1))) void* gas_ptr;
typedef __attribute__((address_space(3))) void* las_ptr;
__device__ __forceinline__ void async_ld16(const _Float16* g, _Float16* l) {
    __builtin_amdgcn_global_load_lds((gas_ptr)g, (las_ptr)l, 16, 0, 0);
}

__global__ __launch_bounds__(256) void mfma_gemm_kernel(const _Float16* __restrict__ Ah,
                                                        const _Float16* __restrict__ Al,
                                                        const _Float16* __restrict__ Bh,
                                                        const _Float16* __restrict__ Bl,
                                                        float* __restrict__ C) {
    __shared__ _Float16 sAh[2 * 4096];   // [parity][128 rows x 32 k]
    __shared__ _Float16 sAl[2 * 4096];
    __shared__ _Float16 sBh[2 * 2048];   // [parity][64 rows x 32 k]
    __shared__ _Float16 sBl[2 * 2048];
    int tid = threadIdx.x;
    int lane = tid & 63;
    int wave = tid >> 6;
    int m0 = blockIdx.x * 128, n0 = blockIdx.y * 64;

    const _Float16* src = (wave == 0) ? Ah : (wave == 1) ? Al : (wave == 2) ? Bh : Bl;
    _Float16* dstb = (wave == 0) ? sAh : (wave == 1) ? sAl : (wave == 2) ? sBh : sBl;
    int psz  = (wave < 2) ? 4096 : 2048;
    int nch  = (wave < 2) ? 8 : 4;
    int row0 = (wave < 2) ? m0 : n0;
    int qg = (lane & 3) ^ ((lane >> 3) & 3);            // swizzled source k-group
    const _Float16* gp = src + (size_t)(row0 + (lane >> 2)) * 768 + qg * 8;

    int wr = wave >> 1, wc = wave & 1;
    int off_lane = (lane & 15) * 64 + (((lane >> 4) ^ ((lane >> 1) & 3)) * 16);  // bytes
    floatx4 acc[4][2];
#pragma unroll
    for (int i = 0; i < 4; ++i)
#pragma unroll
        for (int j = 0; j < 2; ++j)
            acc[i][j] = (floatx4){0.f, 0.f, 0.f, 0.f};

#pragma unroll
    for (int c = 0; c < 8; ++c) {
        if (c < nch) async_ld16(gp + (size_t)c * 16 * 768, dstb + c * 512);
    }

    int parity = 0;
    for (int k0 = 0; k0 < 768; k0 += 32) {
        __syncthreads();
        if (k0 + 32 < 768) {
            _Float16* dst = dstb + (parity ^ 1) * psz;
            const _Float16* g = gp + k0 + 32;
#pragma unroll
            for (int c = 0; c < 8; ++c) {
                if (c < nch) async_ld16(g + (size_t)c * 16 * 768, dst + c * 512);
            }
        }

        const char* bAh = (const char*)sAh + parity * 8192 + wr * 4096 + off_lane;
        const char* bAl = (const char*)sAl + parity * 8192 + wr * 4096 + off_lane;
        const char* bBh = (const char*)sBh + parity * 4096 + wc * 2048 + off_lane;
        const char* bBl = (const char*)sBl + parity * 4096 + wc * 2048 + off_lane;
        half8 a_h[4], a_l[4], b_h[2], b_l[2];
#pragma unroll
        for (int i = 0; i < 4; ++i) {
            a_h[i] = *(const half8*)(bAh + i * 1024);
            a_l[i] = *(const half8*)(bAl + i * 1024);
        }
#pragma unroll
        for (int j = 0; j < 2; ++j) {
            b_h[j] = *(const half8*)(bBh + j * 1024);
            b_l[j] = *(const half8*)(bBl + j * 1024);
        }
#pragma unroll
        for (int i = 0; i < 4; ++i)
#pragma unroll
            for (int j = 0; j < 2; ++j) {
                acc[i][j] = __builtin_amdgcn_mfma_f32_16x16x32_f16(a_h[i], b_h[j], acc[i][j], 0, 0, 0);
                acc[i][j] = __builtin_amdgcn_mfma_f32_16x16x32_f16(a_h[i], b_l[j], acc[i][j], 0, 0, 0);
                acc[i][j] = __builtin_amdgcn_mfma_f32_16x16x32_f16(a_l[i], b_h[j], acc[i][j], 0, 0, 0);
            }
        parity ^= 1;
    }

    int colc = lane & 15, quad = lane >> 4;
#pragma unroll
    for (int i = 0; i < 4; ++i) {
#pragma unroll
        for (int r = 0; r < 4; ++r) {
            int row = m0 + wr * 64 + i * 16 + quad * 4 + r;
            float* Cp = C + (size_t)row * 2304 + n0 + wc * 32 + colc;
#pragma unroll
            for (int j = 0; j < 2; ++j)
                Cp[j * 16] = acc[i][j][r] * INV_SCALE;
        }
    }
}

// ---------------- kernel 3: span scores; one wave per (b,i), depth-2 pipelined rows ---
// Latency fix: E/C rows for step w+1 are prefetched while computing step w; only the
// first row-load round is latency-exposed. No LDS staging (measured neutral in R6).
__global__ __launch_bounds__(256) void score_kernel(const float* __restrict__ X,
                                                    const int* __restrict__ mask,
                                                    const float* __restrict__ b1,
                                                    const float* __restrict__ g1,
                                                    const float* __restrict__ beta1,
                                                    const float* __restrict__ w2,
                                                    const float* __restrict__ b2,
                                                    float* __restrict__ scores) {
    int wave = threadIdx.x >> 6;
    int lane = threadIdx.x & 63;
    int bi = blockIdx.x * 4 + wave;    // 0..4095
    int b = bi >> 9, i = bi & 511;

    const float4* base = (const float4*)(X + (size_t)(b * 512) * 2304);  // row stride 576 f4
    float4 a[3], b1c[3], g1c[3], btc[3], w2c[3], ss[3], e_c[3], c_c[3], e_n[3], c_n[3];
#pragma unroll
    for (int q = 0; q < 3; ++q) {
        int f = lane + q * 64;
        // prefetch row j=i (first iteration's E/C)
        e_c[q] = base[(size_t)i * 576 + 192 + f];
        c_c[q] = base[(size_t)i * 576 + 384 + f];
        a[q]   = base[(size_t)i * 576 + f];
        b1c[q] = ((const float4*)b1)[f];
        g1c[q] = ((const float4*)g1)[f];
        btc[q] = ((const float4*)beta1)[f];
        w2c[q] = ((const float4*)w2)[f];
        ss[q]  = make_float4(0.f, 0.f, 0.f, 0.f);
    }
    float bias2 = b2[0];
    int jcur = i - 1;
    float sc_loc[W_];

#pragma unroll
    for (int w = 0; w < W_; ++w) {
        // prefetch next row (independent loads, fully overlapped with compute below)
        if (w < W_ - 1) {
            int jn = min(i + w + 1, 511);
#pragma unroll
            for (int q = 0; q < 3; ++q) {
                int f = lane + q * 64;
                e_n[q] = base[(size_t)jn * 576 + 192 + f];
                c_n[q] = base[(size_t)jn * 576 + 384 + f];
            }
        }
        int j = min(i + w, 511);
        if (j > jcur) {
#pragma unroll
            for (int q = 0; q < 3; ++q) {
                ss[q].x += c_c[q].x; ss[q].y += c_c[q].y; ss[q].z += c_c[q].z; ss[q].w += c_c[q].w;
            }
            jcur = j;
        }
        float invw = 1.0f / (float)(w + 1);
        float4 h[3];
        float psum = 0.f, psq = 0.f;
#pragma unroll
        for (int q = 0; q < 3; ++q) {
            h[q].x = a[q].x + e_c[q].x + ss[q].x * invw + b1c[q].x;
            h[q].y = a[q].y + e_c[q].y + ss[q].y * invw + b1c[q].y;
            h[q].z = a[q].z + e_c[q].z + ss[q].z * invw + b1c[q].z;
            h[q].w = a[q].w + e_c[q].w + ss[q].w * invw + b1c[q].w;
            psum += h[q].x + h[q].y + h[q].z + h[q].w;
            psq  += h[q].x * h[q].x + h[q].y * h[q].y + h[q].z * h[q].z + h[q].w * h[q].w;
        }
#pragma unroll
        for (int m = 1; m < 64; m <<= 1) {
            psum += __shfl_xor(psum, m, 64);
            psq  += __shfl_xor(psq, m, 64);
        }
        float mean = psum * (1.f / 768.f);
        float var  = psq * (1.f / 768.f) - mean * mean;
        float rstd = rsqrtf(var + EPS_);

        float pd = 0.f;
#pragma unroll
        for (int q = 0; q < 3; ++q) {
            float yx = fmaxf((h[q].x - mean) * rstd * g1c[q].x + btc[q].x, 0.f);
            float yy = fmaxf((h[q].y - mean) * rstd * g1c[q].y + btc[q].y, 0.f);
            float yz = fmaxf((h[q].z - mean) * rstd * g1c[q].z + btc[q].z, 0.f);
            float yw = fmaxf((h[q].w - mean) * rstd * g1c[q].w + btc[q].w, 0.f);
            pd += yx * w2c[q].x + yy * w2c[q].y + yz * w2c[q].z + yw * w2c[q].w;
        }
#pragma unroll
        for (int m = 1; m < 64; m <<= 1) pd += __shfl_xor(pd, m, 64);
        sc_loc[w] = pd + bias2;

        // rotate pipeline
        if (w < W_ - 1) {
#pragma unroll
            for (int q = 0; q < 3; ++q) { e_c[q] = e_n[q]; c_c[q] = c_n[q]; }
        }
    }

    // static-indexed lane select (avoid scratch from sc_loc[lane])
    float outv = 0.f;
#pragma unroll
    for (int w = 0; w < W_; ++w)
        if (lane == w) outv = sc_loc[w];
    if (lane < W_) {
        int w = lane;
        bool ok = (i + w) < 512;
        if (ok) {
            for (int t = 0; t <= w; ++t) ok = ok && (mask[b * 512 + i + t] != 0);
        }
        scores[b * 2560 + i * 5 + w] = ok ? outv : NEG_;
    }
}

// ---------------- kernel 4: per-b top-32 via u64 keys + register heads ----------------
__device__ __forceinline__ uint64_t shfl_xor_u64(uint64_t x, int m) {
    uint32_t lo = (uint32_t)x, hi = (uint32_t)(x >> 32);
    lo = (uint32_t)__shfl_xor((int)lo, m, 64);
    hi = (uint32_t)__shfl_xor((int)hi, m, 64);
    return ((uint64_t)hi << 32) | lo;
}

__global__ __launch_bounds__(256) void topk_kernel(const float* __restrict__ scores,
                                                   float* __restrict__ tops,
                                                   int* __restrict__ topi,
                                                   float* __restrict__ out_masks,
                                                   float* __restrict__ out_scores,
                                                   float* __restrict__ out_spans) {
    int b = blockIdx.x;
    int tid = threadIdx.x;
    int lane = tid & 63;
    int wv = tid >> 6;
    __shared__ uint64_t lists[256 * 9];
    __shared__ uint64_t wmax[4];
    __shared__ uint64_t gS;

    uint64_t v[10];
#pragma unroll
    for (int q = 0; q < 10; ++q) {
        int t = q * 256 + tid;
        float f = scores[b * 2560 + t];
        uint32_t bits = __float_as_uint(f);
        uint32_t mk = bits ^ ((bits & 0x80000000u) ? 0xFFFFFFFFu : 0x80000000u);
        v[q] = ((uint64_t)mk << 32) | (uint64_t)(0xFFFFFFFFu - (uint32_t)t);
    }
#pragma unroll
    for (int p = 0; p < 5; ++p) {
#pragma unroll
        for (int i = 0; i < 9; i += 2) {
            if (v[i] < v[i + 1]) { uint64_t t = v[i]; v[i] = v[i + 1]; v[i + 1] = t; }
        }
#pragma unroll
        for (int i = 1; i < 9; i += 2) {
            if (v[i] < v[i + 1]) { uint64_t t = v[i]; v[i] = v[i + 1]; v[i + 1] = t; }
        }
    }
#pragma unroll
    for (int j = 0; j < 9; ++j) lists[tid * 9 + j] = v[j + 1];
    uint64_t my = v[0];
    int h = 0;

    for (int k = 0; k < K_; ++k) {
        uint64_t m = my;
#pragma unroll
        for (int s = 1; s < 64; s <<= 1) {
            uint64_t o = shfl_xor_u64(m, s);
            if (o > m) m = o;
        }
        if (lane == 0) wmax[wv] = m;
        __syncthreads();
        if (tid == 0) {
            uint64_t g = wmax[0];
#pragma unroll
            for (int q = 1; q < 4; ++q) if (wmax[q] > g) g = wmax[q];
            gS = g;
            uint32_t mk = (uint32_t)(g >> 32);
            uint32_t bits = mk ^ ((mk & 0x80000000u) ? 0x80000000u : 0xFFFFFFFFu);
            float tv = __uint_as_float(bits);
            int tix = (int)(0xFFFFFFFFu - (uint32_t)(g & 0xFFFFFFFFu));
            tops[b * 32 + k] = tv;
            topi[b * 32 + k] = tix;
            bool mm = tv > (NEG_ * 0.5f);
            out_masks[b * 32 + k] = mm ? 1.0f : 0.0f;
            out_scores[b * 32 + k] = mm ? tv : -10.0f;
            int tI = tix / 5, tw = tix % 5;
            out_spans[(b * 32 + k) * 2 + 0] = mm ? (float)tI : 0.0f;
            out_spans[(b * 32 + k) * 2 + 1] = mm ? (float)(tI + tw) : 0.0f;
        }
        __syncthreads();
        uint64_t g = gS;
        if (my == g) {
            my = (h < 9) ? lists[tid * 9 + h] : 0ull;
            ++h;
        }
    }
}

// ---------------- kernel 5: gather phrase mean-embeddings into Embs[256][768] ---------
__global__ __launch_bounds__(256) void gather_emb_kernel(const float* __restrict__ hidden,
                                                         const float* __restrict__ tops,
                                                         const int* __restrict__ topi,
                                                         float* __restrict__ Embs) {
    int bk = blockIdx.x;            // 0..255
    int b = bk >> 5;
    int tid = threadIdx.x;
    int idx = topi[bk];
    bool valid = tops[bk] > (NEG_ * 0.5f);
    int tI = idx / 5, tw = idx % 5;
    int jend = min(tI + tw, L_ - 1);
    float inv = 1.0f / (float)(tw + 1);
#pragma unroll
    for (int q = 0; q < 3; ++q) {
        int c = tid + q * 256;
        float s = 0.f;
        if (valid) {
            for (int l = tI; l <= jend; ++l) s += hidden[(size_t)(b * 512 + l) * 768 + c];
            s *= inv;
        }
        Embs[(size_t)bk * 768 + c] = s;
    }
}

// ---------------- kernel 6: Y[256][640] = Embs @ [wg1|wp] + [bg1|bp] ----------------
__global__ __launch_bounds__(256) void phrase_gemm_kernel(const float* __restrict__ Embs,
                                                          const float* __restrict__ wg1,
                                                          const float* __restrict__ bg1,
                                                          const float* __restrict__ wp,
                                                          const float* __restrict__ bp,
                                                          float* __restrict__ Y) {
    __shared__ float As[32][34];   // [k][r]
    __shared__ float Bs[32][64];   // [k][c]
    int tid = threadIdx.x;
    int m0 = blockIdx.x * 32;
    int cn0 = blockIdx.y * 64;
    const float* Wp; const float* biasp; int ldw;
    if (cn0 < 384) { Wp = wg1 + cn0;        biasp = bg1 + cn0;        ldw = 384; }
    else           { Wp = wp + (cn0 - 384); biasp = bp + (cn0 - 384); ldw = 256; }

    int tx = tid & 15;       // cols tx*4
    int ty = tid >> 4;       // rows ty*2
    int ar = tid >> 3, akq = (tid & 7) * 4;
    int bk = tid >> 3, bcq = (tid & 7) * 8;
    float acc[2][4] = {};

    for (int k0 = 0; k0 < 768; k0 += 32) {
        float4 av  = *(const float4*)(Embs + (size_t)(m0 + ar) * 768 + k0 + akq);
        float4 bv0 = *(const float4*)(Wp + (size_t)(k0 + bk) * ldw + bcq);
        float4 bv1 = *(const float4*)(Wp + (size_t)(k0 + bk) * ldw + bcq + 4);
        __syncthreads();
        As[akq + 0][ar] = av.x;
        As[akq + 1][ar] = av.y;
        As[akq + 2][ar] = av.z;
        As[akq + 3][ar] = av.w;
        *(float4*)&Bs[bk][bcq]     = bv0;
        *(float4*)&Bs[bk][bcq + 4] = bv1;
        __syncthreads();
#pragma unroll
        for (int kk = 0; kk < 32; ++kk) {
            float2 a = *(const float2*)&As[kk][ty * 2];
            float4 b = *(const float4*)&Bs[kk][tx * 4];
            acc[0][0] += a.x * b.x; acc[0][1] += a.x * b.y; acc[0][2] += a.x * b.z; acc[0][3] += a.x * b.w;
            acc[1][0] += a.y * b.x; acc[1][1] += a.y * b.y; acc[1][2] += a.y * b.z; acc[1][3] += a.y * b.w;
        }
    }
#pragma unroll
    for (int i = 0; i < 2; ++i) {
        float* Yp = Y + (size_t)(m0 + ty * 2 + i) * 640 + cn0 + tx * 4;
        float4 o = make_float4(acc[i][0] + biasp[tx * 4 + 0], acc[i][1] + biasp[tx * 4 + 1],
                               acc[i][2] + biasp[tx * 4 + 2], acc[i][3] + biasp[tx * 4 + 3]);
        *(float4*)Yp = o;
    }
}

// ---------------- kernel 7: per-row gate (tanh . wg2) + LN of projection --------------
__global__ __launch_bounds__(256) void phrase_post_kernel(const float* __restrict__ Y,
                                                          const float* __restrict__ wg2,
                                                          const float* __restrict__ bg2,
                                                          const float* __restrict__ tops,
                                                          const float* __restrict__ gout,
                                                          const float* __restrict__ bout,
                                                          float* __restrict__ gate,
                                                          float* __restrict__ out_embeds) {
    int wv = threadIdx.x >> 6, lane = threadIdx.x & 63;
    int row = blockIdx.x * 4 + wv;   // 64 blocks -> 256 rows
    const float* Yrow = Y + (size_t)row * 640;

    float s = 0.f;
#pragma unroll
    for (int q = 0; q < 6; ++q) {
        int c = lane + q * 64;
        s += tanhf(Yrow[c]) * wg2[c];
    }
#pragma unroll
    for (int m = 1; m < 64; m <<= 1) s += __shfl_xor(s, m, 64);
    if (lane == 0) {
        bool valid = tops[row] > (NEG_ * 0.5f);
        gate[row] = valid ? (s + bg2[0]) : -1e9f;
    }

    float4 p = *(const float4*)(Yrow + 384 + lane * 4);
    float sm = p.x + p.y + p.z + p.w;
#pragma unroll
    for (int m = 1; m < 64; m <<= 1) sm += __shfl_xor(sm, m, 64);
    float mean = sm * (1.f / 256.f);
    float dx = p.x - mean, dy = p.y - mean, dz = p.z - mean, dw = p.w - mean;
    float v = dx * dx + dy * dy + dz * dz + dw * dw;
#pragma unroll
    for (int m = 1; m < 64; m <<= 1) v += __shfl_xor(v, m, 64);
    float rstd = rsqrtf(v * (1.f / 256.f) + EPS_);
    int c = lane * 4;
    float4 o;
    o.x = dx * rstd * gout[c]     + bout[c];
    o.y = dy * rstd * gout[c + 1] + bout[c + 1];
    o.z = dz * rstd * gout[c + 2] + bout[c + 2];
    o.w = dw * rstd * gout[c + 3] + bout[c + 3];
    *(float4*)(out_embeds + (size_t)row * 256 + c) = o;
}

// ---------------- kernel 8: softmax over K per b ----------------
__global__ void attn_kernel(const float* __restrict__ gate, float* __restrict__ out_attn) {
    int b = threadIdx.x;
    if (b < 8) {
        float mx = -FLT_MAX;
        for (int k = 0; k < 32; ++k) mx = fmaxf(mx, gate[b * 32 + k]);
        float e[32];
        float s = 0.f;
        for (int k = 0; k < 32; ++k) { e[k] = expf(gate[b * 32 + k] - mx); s += e[k]; }
        float inv = 1.f / s;
        for (int k = 0; k < 32; ++k) out_attn[b * 32 + k] = e[k] * inv;
    }
}

extern "C" void kernel_launch(void* const* d_in, const int* in_sizes, int n_in,
                              void* d_out, int out_size, void* d_ws, size_t ws_size,
                              hipStream_t stream) {
    const float* hidden = (const float*)d_in[0];
    const int*   amask  = (const int*)d_in[1];
    const float* w1     = (const float*)d_in[2];
    const float* b1     = (const float*)d_in[3];
    const float* g1     = (const float*)d_in[4];
    const float* beta1  = (const float*)d_in[5];
    const float* w2     = (const float*)d_in[6];
    const float* b2     = (const float*)d_in[7];
    const float* wp     = (const float*)d_in[8];
    const float* bp     = (const float*)d_in[9];
    const float* wg1    = (const float*)d_in[10];
    const float* bg1    = (const float*)d_in[11];
    const float* wg2    = (const float*)d_in[12];
    const float* bg2    = (const float*)d_in[13];
    const float* gout   = (const float*)d_in[14];
    const float* bout   = (const float*)d_in[15];

    float* ws = (float*)d_ws;
    float*     X    = ws + OFF_X;
    _Float16*  ah   = (_Float16*)(ws + OFF_AH);
    _Float16*  al   = (_Float16*)(ws + OFF_AL);
    _Float16*  bh   = (_Float16*)(ws + OFF_BH);
    _Float16*  bl   = (_Float16*)(ws + OFF_BL);
    float*     sc   = ws + OFF_SC;
    float*     ts   = ws + OFF_TS;
    int*       ti   = (int*)(ws + OFF_TI);
    float*     gl   = ws + OFF_GL;
    float*     Embs = ws + OFF_EMB;
    float*     Y    = ws + OFF_Y;

    float* out = (float*)d_out;
    float* out_embeds = out;                   // 8*32*256 = 65536
    float* out_masks  = out + 65536;           // 256
    float* out_attn   = out + 65792;           // 256
    float* out_scores = out + 66048;           // 256
    float* out_spans  = out + 66304;           // 512

    prep_kernel<<<3504, 256, 0, stream>>>(hidden, w1, ah, al, bh, bl);
    mfma_gemm_kernel<<<dim3(32, 36), 256, 0, stream>>>(ah, al, bh, bl, X);
    score_kernel<<<1024, 256, 0, stream>>>(X, amask, b1, g1, beta1, w2, b2, sc);
    topk_kernel<<<8, 256, 0, stream>>>(sc, ts, ti, out_masks, out_scores, out_spans);
    gather_emb_kernel<<<256, 256, 0, stream>>>(hidden, ts, ti, Embs);
    phrase_gemm_kernel<<<dim3(8, 10), 256, 0, stream>>>(Embs, wg1, bg1, wp, bp, Y);
    phrase_post_kernel<<<64, 256, 0, stream>>>(Y, wg2, bg2, ts, gout, bout, gl, out_embeds);
    attn_kernel<<<1, 64, 0, stream>>>(gl, out_attn);
}